// Round 1
// baseline (987.469 us; speedup 1.0000x reference)
//
#include <hip/hip_runtime.h>
#include <math.h>

#define MTOT 32768   // BATCH * SEQ_LEN
#define KD 512       // INPUT_DIM
#define HD 512       // HIDDEN_DIM
#define NB 8         // BATCH
#define TS 4096      // SEQ_LEN
#define NCHUNK 64
#define TCHUNK 64    // NCHUNK*TCHUNK == TS

// ---------------- fused input GEMMs: a_coef, b_coef, xD ----------------
// a_out[m,h] = 1 - g*(1-A[h]),  g = clip(sigmoid(x[m,:]·Wg[h,:]), .05, .95)
// b_out[m,h] = g * (x[m,:]·B[h,:] + bias_h[h])
// xd_out[m,h] = x[m,:]·D[h,:]          (written into d_out, consumed later)
__global__ __launch_bounds__(256) void fused_in_gemm(
    const float* __restrict__ x, const float* __restrict__ Bw,
    const float* __restrict__ Dw, const float* __restrict__ Wg,
    const float* __restrict__ Avec, const float* __restrict__ bias_h,
    float* __restrict__ a_out, float* __restrict__ b_out,
    float* __restrict__ xd_out)
{
    __shared__ float Xs[16][68];   // [k][m], stride 68 floats = 272B (16B aligned, 2-way banks)
    __shared__ float Bs[16][68];   // [k][h]
    __shared__ float Ds[16][68];
    __shared__ float Gs[16][68];
    const int tid = threadIdx.x;
    const int tx  = tid & 15;      // output col group (h)
    const int ty  = tid >> 4;      // output row group (m)
    const int m0  = blockIdx.x * 64;
    const int n0  = blockIdx.y * 64;
    const int lr  = tid >> 2;          // 0..63 tile row for loads
    const int lc  = (tid & 3) << 2;    // 0,4,8,12 k-offset for loads
    float accB[4][4] = {};
    float accD[4][4] = {};
    float accG[4][4] = {};
    for (int kk = 0; kk < KD; kk += 16) {
        const float4 xv = *(const float4*)(x  + (size_t)(m0 + lr) * KD + kk + lc);
        const float4 bv = *(const float4*)(Bw + (size_t)(n0 + lr) * KD + kk + lc);
        const float4 dv = *(const float4*)(Dw + (size_t)(n0 + lr) * KD + kk + lc);
        const float4 gv = *(const float4*)(Wg + (size_t)(n0 + lr) * KD + kk + lc);
        __syncthreads();
        Xs[lc+0][lr] = xv.x; Xs[lc+1][lr] = xv.y; Xs[lc+2][lr] = xv.z; Xs[lc+3][lr] = xv.w;
        Bs[lc+0][lr] = bv.x; Bs[lc+1][lr] = bv.y; Bs[lc+2][lr] = bv.z; Bs[lc+3][lr] = bv.w;
        Ds[lc+0][lr] = dv.x; Ds[lc+1][lr] = dv.y; Ds[lc+2][lr] = dv.z; Ds[lc+3][lr] = dv.w;
        Gs[lc+0][lr] = gv.x; Gs[lc+1][lr] = gv.y; Gs[lc+2][lr] = gv.z; Gs[lc+3][lr] = gv.w;
        __syncthreads();
        #pragma unroll
        for (int k = 0; k < 16; ++k) {
            float xr[4], br[4], dr[4], gr[4];
            #pragma unroll
            for (int j = 0; j < 4; ++j) {
                xr[j] = Xs[k][ty*4 + j];
                br[j] = Bs[k][tx*4 + j];
                dr[j] = Ds[k][tx*4 + j];
                gr[j] = Gs[k][tx*4 + j];
            }
            #pragma unroll
            for (int i = 0; i < 4; ++i) {
                #pragma unroll
                for (int j = 0; j < 4; ++j) {
                    accB[i][j] = fmaf(xr[i], br[j], accB[i][j]);
                    accD[i][j] = fmaf(xr[i], dr[j], accD[i][j]);
                    accG[i][j] = fmaf(xr[i], gr[j], accG[i][j]);
                }
            }
        }
    }
    const int h4 = n0 + tx * 4;
    const float4 Av  = *(const float4*)(Avec  + h4);
    const float4 bhv = *(const float4*)(bias_h + h4);
    const float Aarr[4]  = {Av.x, Av.y, Av.z, Av.w};
    const float bharr[4] = {bhv.x, bhv.y, bhv.z, bhv.w};
    #pragma unroll
    for (int i = 0; i < 4; ++i) {
        const size_t row = (size_t)(m0 + ty*4 + i) * HD + h4;
        float av[4], bvv[4];
        #pragma unroll
        for (int j = 0; j < 4; ++j) {
            float g = 1.0f / (1.0f + expf(-accG[i][j]));
            g = fminf(fmaxf(g, 0.05f), 0.95f);
            av[j]  = 1.0f - g * (1.0f - Aarr[j]);
            bvv[j] = g * (accB[i][j] + bharr[j]);
        }
        *(float4*)(a_out  + row) = make_float4(av[0],  av[1],  av[2],  av[3]);
        *(float4*)(b_out  + row) = make_float4(bvv[0], bvv[1], bvv[2], bvv[3]);
        *(float4*)(xd_out + row) = make_float4(accD[i][0], accD[i][1], accD[i][2], accD[i][3]);
    }
}

// ---------------- chunked parallel scan ----------------
// pass1: per (b,h,chunk) compute P = prod(a), S = scan-end starting from 0
__global__ __launch_bounds__(256) void scan_pass1(
    const float* __restrict__ a_buf, const float* __restrict__ b_buf,
    float* __restrict__ chP, float* __restrict__ chS)
{
    const int g = blockIdx.x * blockDim.x + threadIdx.x;  // 0 .. 8*512*64-1
    const int h = g & (HD - 1);
    const int rest = g >> 9;
    const int b = rest & (NB - 1);
    const int c = rest >> 3;
    size_t idx = ((size_t)(b * TS + c * TCHUNK)) * HD + h;
    float P = 1.0f, S = 0.0f;
    #pragma unroll 4
    for (int t = 0; t < TCHUNK; ++t) {
        const float av = a_buf[idx];
        const float bv = b_buf[idx];
        P *= av;
        S = fmaf(av, S, bv);
        idx += HD;
    }
    const int bh = b * HD + h;
    chP[(size_t)c * (NB * HD) + bh] = P;
    chS[(size_t)c * (NB * HD) + bh] = S;
}

// pass2: serial chain over chunks -> entry state per chunk
__global__ __launch_bounds__(256) void scan_pass2(
    const float* __restrict__ chP, const float* __restrict__ chS,
    float* __restrict__ hin)
{
    const int bh = blockIdx.x * blockDim.x + threadIdx.x;  // 0..4095
    float h = 0.0f;
    for (int c = 0; c < NCHUNK; ++c) {
        hin[(size_t)c * (NB * HD) + bh] = h;
        h = fmaf(chP[(size_t)c * (NB * HD) + bh], h, chS[(size_t)c * (NB * HD) + bh]);
    }
}

// pass3: replay with entry state, overwrite b_buf with hs
__global__ __launch_bounds__(256) void scan_pass3(
    const float* __restrict__ a_buf, float* __restrict__ b_buf,
    const float* __restrict__ hin)
{
    const int g = blockIdx.x * blockDim.x + threadIdx.x;
    const int h = g & (HD - 1);
    const int rest = g >> 9;
    const int b = rest & (NB - 1);
    const int c = rest >> 3;
    size_t idx = ((size_t)(b * TS + c * TCHUNK)) * HD + h;
    const int bh = b * HD + h;
    float hv = hin[(size_t)c * (NB * HD) + bh];
    #pragma unroll 4
    for (int t = 0; t < TCHUNK; ++t) {
        hv = fmaf(a_buf[idx], hv, b_buf[idx]);
        b_buf[idx] = hv;
        idx += HD;
    }
}

// ---------------- output GEMM: y = (hs@C^T + xD + bias_y) * scale ----------------
__global__ __launch_bounds__(256) void out_gemm(
    const float* __restrict__ hs, const float* __restrict__ Cw,
    const float* __restrict__ bias_y, float* __restrict__ y /* holds xD */)
{
    __shared__ float Hs[16][68];
    __shared__ float Cs[16][68];
    const int tid = threadIdx.x;
    const int tx  = tid & 15;
    const int ty  = tid >> 4;
    const int m0  = blockIdx.x * 64;
    const int n0  = blockIdx.y * 64;
    const int lr  = tid >> 2;
    const int lc  = (tid & 3) << 2;
    float acc[4][4] = {};
    for (int kk = 0; kk < HD; kk += 16) {
        const float4 hv = *(const float4*)(hs + (size_t)(m0 + lr) * HD + kk + lc);
        const float4 cv = *(const float4*)(Cw + (size_t)(n0 + lr) * HD + kk + lc);
        __syncthreads();
        Hs[lc+0][lr] = hv.x; Hs[lc+1][lr] = hv.y; Hs[lc+2][lr] = hv.z; Hs[lc+3][lr] = hv.w;
        Cs[lc+0][lr] = cv.x; Cs[lc+1][lr] = cv.y; Cs[lc+2][lr] = cv.z; Cs[lc+3][lr] = cv.w;
        __syncthreads();
        #pragma unroll
        for (int k = 0; k < 16; ++k) {
            float hr[4], cr[4];
            #pragma unroll
            for (int j = 0; j < 4; ++j) {
                hr[j] = Hs[k][ty*4 + j];
                cr[j] = Cs[k][tx*4 + j];
            }
            #pragma unroll
            for (int i = 0; i < 4; ++i)
                #pragma unroll
                for (int j = 0; j < 4; ++j)
                    acc[i][j] = fmaf(hr[i], cr[j], acc[i][j]);
        }
    }
    const float scale = 0.04419417382415922f;  // 1/sqrt(512)
    const int o4 = n0 + tx * 4;
    const float4 byv = *(const float4*)(bias_y + o4);
    const float barr[4] = {byv.x, byv.y, byv.z, byv.w};
    #pragma unroll
    for (int i = 0; i < 4; ++i) {
        const size_t row = (size_t)(m0 + ty*4 + i) * HD + o4;
        float4 xd = *(const float4*)(y + row);
        const float xda[4] = {xd.x, xd.y, xd.z, xd.w};
        float r[4];
        #pragma unroll
        for (int j = 0; j < 4; ++j)
            r[j] = (acc[i][j] + xda[j] + barr[j]) * scale;
        *(float4*)(y + row) = make_float4(r[0], r[1], r[2], r[3]);
    }
}

extern "C" void kernel_launch(void* const* d_in, const int* in_sizes, int n_in,
                              void* d_out, int out_size, void* d_ws, size_t ws_size,
                              hipStream_t stream) {
    const float* x      = (const float*)d_in[0];
    const float* Avec   = (const float*)d_in[1];
    const float* Bw     = (const float*)d_in[2];
    const float* Cw     = (const float*)d_in[3];
    const float* Dw     = (const float*)d_in[4];
    const float* Wg     = (const float*)d_in[5];
    const float* bias_h = (const float*)d_in[6];
    const float* bias_y = (const float*)d_in[7];
    float* y = (float*)d_out;

    float* a_buf = (float*)d_ws;                        // 16M floats (64 MiB)
    float* b_buf = a_buf + (size_t)MTOT * HD;           // 16M floats (64 MiB), becomes hs
    float* chP   = b_buf + (size_t)MTOT * HD;           // 262144 floats
    float* chS   = chP + (size_t)NCHUNK * NB * HD;
    float* hin   = chS + (size_t)NCHUNK * NB * HD;

    dim3 gg(MTOT / 64, HD / 64), gb(256);
    fused_in_gemm<<<gg, gb, 0, stream>>>(x, Bw, Dw, Wg, Avec, bias_h, a_buf, b_buf, y);

    const int scan_threads = NB * HD * NCHUNK;          // 262144
    scan_pass1<<<scan_threads / 256, 256, 0, stream>>>(a_buf, b_buf, chP, chS);
    scan_pass2<<<(NB * HD) / 256, 256, 0, stream>>>(chP, chS, hin);
    scan_pass3<<<scan_threads / 256, 256, 0, stream>>>(a_buf, b_buf, hin);

    out_gemm<<<gg, gb, 0, stream>>>(b_buf, Cw, bias_y, y);
}

// Round 2
// 290.399 us; speedup vs baseline: 3.4004x; 3.4004x over previous
//
#include <hip/hip_runtime.h>
#include <math.h>

#define MTOT 32768   // BATCH * SEQ_LEN
#define KD 512       // INPUT_DIM
#define HD 512       // HIDDEN_DIM
#define NB 8         // BATCH
#define TS 4096      // SEQ_LEN
#define NCHUNK 64
#define TCHUNK 64

typedef __attribute__((ext_vector_type(8))) short bf16x8;
typedef __attribute__((ext_vector_type(4))) float f32x4;
typedef __attribute__((ext_vector_type(4))) unsigned short us4;

// async 16B global->LDS copy: lane l writes lds_base + l*16
#define GLD16(gsrc, ldst) __builtin_amdgcn_global_load_lds( \
    (const __attribute__((address_space(1))) void*)(gsrc),   \
    (__attribute__((address_space(3))) void*)(ldst), 16, 0, 0)

__device__ __forceinline__ unsigned short f2bf(float f) {
    unsigned u = __float_as_uint(f);
    return (unsigned short)((u + 0x7FFFu + ((u >> 16) & 1u)) >> 16);
}

// ---------------- casts ----------------
__global__ __launch_bounds__(256) void cast_x(const float* __restrict__ src,
                                              unsigned short* __restrict__ dst) {
    const int i = (blockIdx.x * 256 + threadIdx.x) * 4;
    float4 v = *(const float4*)(src + i);
    us4 o; o.x = f2bf(v.x); o.y = f2bf(v.y); o.z = f2bf(v.z); o.w = f2bf(v.w);
    *(us4*)(dst + i) = o;
}

__global__ __launch_bounds__(256) void cast_w(const float* __restrict__ B,
                                              const float* __restrict__ D,
                                              const float* __restrict__ G,
                                              const float* __restrict__ C,
                                              unsigned short* __restrict__ dst) {
    const float* srcs[4] = {B, D, G, C};
    const float* s = srcs[blockIdx.y];
    unsigned short* d = dst + (size_t)blockIdx.y * (HD * KD);
    const int i = (blockIdx.x * 256 + threadIdx.x) * 4;
    float4 v = *(const float4*)(s + i);
    us4 o; o.x = f2bf(v.x); o.y = f2bf(v.y); o.z = f2bf(v.z); o.w = f2bf(v.w);
    *(us4*)(d + i) = o;
}

// ---------------- fused input GEMMs (bf16 MFMA) ----------------
// O_B = x@B^T, O_D = x@D^T, O_G = x@Wg^T, then epilogue -> a_coef, b_coef, xD
// block tile: 128(M) x 64(N), BK=64, 4 waves each 64x32 per GEMM
__global__ __launch_bounds__(256, 2) void in_gemm_mfma(
    const short* __restrict__ xb, const short* __restrict__ wmat,  // wmat: B,D,G packed
    const float* __restrict__ Avec, const float* __restrict__ bias_h,
    float* __restrict__ a_out, float* __restrict__ b_out, float* __restrict__ xd_out)
{
    __shared__ __align__(16) short Xs[128 * 64];
    __shared__ __align__(16) short Ws[3][64 * 64];
    const int tid = threadIdx.x;
    const int w = tid >> 6, l = tid & 63;
    const int m0 = blockIdx.x * 128;
    const int n0 = blockIdx.y * 64;
    const int wm = (w & 1) * 64;
    const int wn = (w >> 1) * 32;

    // staging source offsets (elements), swizzled: slot s holds (r=s>>3, g=(s&7)^(r&7))
    int xsrc[4], xdst[4];
    #pragma unroll
    for (int j = 0; j < 4; ++j) {
        const int s = (w * 4 + j) * 64 + l;
        const int r = s >> 3, g = (s & 7) ^ (r & 7);
        xsrc[j] = (m0 + r) * KD + g * 8;
        xdst[j] = (w * 4 + j) * 64 * 8;   // shorts
    }
    int wsrc[2], wdst[2];
    #pragma unroll
    for (int j = 0; j < 2; ++j) {
        const int s = (w * 2 + j) * 64 + l;
        const int r = s >> 3, g = (s & 7) ^ (r & 7);
        wsrc[j] = (n0 + r) * KD + g * 8;
        wdst[j] = (w * 2 + j) * 64 * 8;
    }

    f32x4 acc[3][4][2];
    #pragma unroll
    for (int a = 0; a < 3; ++a)
        #pragma unroll
        for (int i = 0; i < 4; ++i)
            #pragma unroll
            for (int j = 0; j < 2; ++j) acc[a][i][j] = (f32x4)0.0f;

    for (int kk = 0; kk < KD; kk += 64) {
        __syncthreads();
        #pragma unroll
        for (int j = 0; j < 4; ++j) GLD16(xb + xsrc[j] + kk, Xs + xdst[j]);
        #pragma unroll
        for (int mat = 0; mat < 3; ++mat)
            #pragma unroll
            for (int j = 0; j < 2; ++j)
                GLD16(wmat + (size_t)mat * (HD * KD) + wsrc[j] + kk, &Ws[mat][wdst[j]]);
        __syncthreads();
        #pragma unroll
        for (int kc = 0; kc < 2; ++kc) {
            const int g = kc * 4 + (l >> 4);
            bf16x8 af[4];
            #pragma unroll
            for (int mt = 0; mt < 4; ++mt) {
                const int r = wm + mt * 16 + (l & 15);
                af[mt] = *(const bf16x8*)(Xs + r * 64 + ((g ^ (r & 7)) * 8));
            }
            #pragma unroll
            for (int mat = 0; mat < 3; ++mat) {
                #pragma unroll
                for (int nt = 0; nt < 2; ++nt) {
                    const int r = wn + nt * 16 + (l & 15);
                    bf16x8 bf = *(const bf16x8*)(&Ws[mat][r * 64 + ((g ^ (r & 7)) * 8)]);
                    #pragma unroll
                    for (int mt = 0; mt < 4; ++mt)
                        acc[mat][mt][nt] = __builtin_amdgcn_mfma_f32_16x16x32_bf16(
                            af[mt], bf, acc[mat][mt][nt], 0, 0, 0);
                }
            }
        }
    }

    // epilogue: C/D layout col = l&15, row = (l>>4)*4 + reg
    #pragma unroll
    for (int nt = 0; nt < 2; ++nt) {
        const int n = n0 + wn + nt * 16 + (l & 15);
        const float An = Avec[n], bh = bias_h[n];
        #pragma unroll
        for (int mt = 0; mt < 4; ++mt) {
            #pragma unroll
            for (int r = 0; r < 4; ++r) {
                const int m = m0 + wm + mt * 16 + (l >> 4) * 4 + r;
                const size_t off = (size_t)m * HD + n;
                const float vB = acc[0][mt][nt][r];
                const float vD = acc[1][mt][nt][r];
                const float vG = acc[2][mt][nt][r];
                float g = 1.0f / (1.0f + expf(-vG));
                g = fminf(fmaxf(g, 0.05f), 0.95f);
                a_out[off]  = 1.0f - g * (1.0f - An);
                b_out[off]  = g * (vB + bh);
                xd_out[off] = vD;
            }
        }
    }
}

// ---------------- chunked parallel scan (fp32) ----------------
__global__ __launch_bounds__(256) void scan_pass1(
    const float* __restrict__ a_buf, const float* __restrict__ b_buf,
    float* __restrict__ chP, float* __restrict__ chS)
{
    const int g = blockIdx.x * blockDim.x + threadIdx.x;
    const int h = g & (HD - 1);
    const int rest = g >> 9;
    const int b = rest & (NB - 1);
    const int c = rest >> 3;
    size_t idx = ((size_t)(b * TS + c * TCHUNK)) * HD + h;
    float P = 1.0f, S = 0.0f;
    #pragma unroll 4
    for (int t = 0; t < TCHUNK; ++t) {
        const float av = a_buf[idx];
        const float bv = b_buf[idx];
        P *= av;
        S = fmaf(av, S, bv);
        idx += HD;
    }
    const int bh = b * HD + h;
    chP[(size_t)c * (NB * HD) + bh] = P;
    chS[(size_t)c * (NB * HD) + bh] = S;
}

__global__ __launch_bounds__(256) void scan_pass2(
    const float* __restrict__ chP, const float* __restrict__ chS,
    float* __restrict__ hin)
{
    const int bh = blockIdx.x * blockDim.x + threadIdx.x;
    float h = 0.0f;
    for (int c = 0; c < NCHUNK; ++c) {
        hin[(size_t)c * (NB * HD) + bh] = h;
        h = fmaf(chP[(size_t)c * (NB * HD) + bh], h, chS[(size_t)c * (NB * HD) + bh]);
    }
}

// pass3: replay, write hs as bf16
__global__ __launch_bounds__(256) void scan_pass3(
    const float* __restrict__ a_buf, const float* __restrict__ b_buf,
    const float* __restrict__ hin, unsigned short* __restrict__ hs_out)
{
    const int g = blockIdx.x * blockDim.x + threadIdx.x;
    const int h = g & (HD - 1);
    const int rest = g >> 9;
    const int b = rest & (NB - 1);
    const int c = rest >> 3;
    size_t idx = ((size_t)(b * TS + c * TCHUNK)) * HD + h;
    const int bh = b * HD + h;
    float hv = hin[(size_t)c * (NB * HD) + bh];
    #pragma unroll 4
    for (int t = 0; t < TCHUNK; ++t) {
        hv = fmaf(a_buf[idx], hv, b_buf[idx]);
        hs_out[idx] = f2bf(hv);
        idx += HD;
    }
}

// ---------------- output GEMM (bf16 MFMA): y = (hs@C^T + xD + bias_y)*scale ----------------
// block tile 128x128, BK=64, 4 waves each 64x64
__global__ __launch_bounds__(256, 2) void out_gemm_mfma(
    const short* __restrict__ hs, const short* __restrict__ Cb,
    const float* __restrict__ bias_y, float* __restrict__ y /* holds xD */)
{
    __shared__ __align__(16) short Hs[128 * 64];
    __shared__ __align__(16) short Cs[128 * 64];
    const int tid = threadIdx.x;
    const int w = tid >> 6, l = tid & 63;
    const int m0 = blockIdx.x * 128;
    const int n0 = blockIdx.y * 128;
    const int wm = (w & 1) * 64;
    const int wn = (w >> 1) * 64;

    int src_h[4], src_c[4], dst_s[4];
    #pragma unroll
    for (int j = 0; j < 4; ++j) {
        const int s = (w * 4 + j) * 64 + l;
        const int r = s >> 3, g = (s & 7) ^ (r & 7);
        src_h[j] = (m0 + r) * HD + g * 8;
        src_c[j] = (n0 + r) * HD + g * 8;
        dst_s[j] = (w * 4 + j) * 64 * 8;
    }

    f32x4 acc[4][4];
    #pragma unroll
    for (int i = 0; i < 4; ++i)
        #pragma unroll
        for (int j = 0; j < 4; ++j) acc[i][j] = (f32x4)0.0f;

    for (int kk = 0; kk < HD; kk += 64) {
        __syncthreads();
        #pragma unroll
        for (int j = 0; j < 4; ++j) {
            GLD16(hs + src_h[j] + kk, Hs + dst_s[j]);
            GLD16(Cb + src_c[j] + kk, Cs + dst_s[j]);
        }
        __syncthreads();
        #pragma unroll
        for (int kc = 0; kc < 2; ++kc) {
            const int g = kc * 4 + (l >> 4);
            bf16x8 af[4], bf[4];
            #pragma unroll
            for (int t = 0; t < 4; ++t) {
                const int ra = wm + t * 16 + (l & 15);
                af[t] = *(const bf16x8*)(Hs + ra * 64 + ((g ^ (ra & 7)) * 8));
                const int rb = wn + t * 16 + (l & 15);
                bf[t] = *(const bf16x8*)(Cs + rb * 64 + ((g ^ (rb & 7)) * 8));
            }
            #pragma unroll
            for (int mt = 0; mt < 4; ++mt)
                #pragma unroll
                for (int nt = 0; nt < 4; ++nt)
                    acc[mt][nt] = __builtin_amdgcn_mfma_f32_16x16x32_bf16(
                        af[mt], bf[nt], acc[mt][nt], 0, 0, 0);
        }
    }

    const float scale = 0.04419417382415922f;  // 1/sqrt(512)
    #pragma unroll
    for (int nt = 0; nt < 4; ++nt) {
        const int n = n0 + wn + nt * 16 + (l & 15);
        const float by = bias_y[n];
        #pragma unroll
        for (int mt = 0; mt < 4; ++mt) {
            #pragma unroll
            for (int r = 0; r < 4; ++r) {
                const int m = m0 + wm + mt * 16 + (l >> 4) * 4 + r;
                const size_t off = (size_t)m * HD + n;
                y[off] = (acc[mt][nt][r] + y[off] + by) * scale;
            }
        }
    }
}

extern "C" void kernel_launch(void* const* d_in, const int* in_sizes, int n_in,
                              void* d_out, int out_size, void* d_ws, size_t ws_size,
                              hipStream_t stream) {
    const float* x      = (const float*)d_in[0];
    const float* Avec   = (const float*)d_in[1];
    const float* Bw     = (const float*)d_in[2];
    const float* Cw     = (const float*)d_in[3];
    const float* Dw     = (const float*)d_in[4];
    const float* Wg     = (const float*)d_in[5];
    const float* bias_h = (const float*)d_in[6];
    const float* bias_y = (const float*)d_in[7];
    float* y = (float*)d_out;

    float* a_buf = (float*)d_ws;                              // 64 MiB
    float* b_buf = a_buf + (size_t)MTOT * HD;                 // 64 MiB
    unsigned short* x16 = (unsigned short*)(b_buf + (size_t)MTOT * HD);  // 32 MiB, reused as hs
    unsigned short* w16 = x16 + (size_t)MTOT * HD;            // 2 MiB: B,D,G,C bf16
    float* chP = (float*)(w16 + (size_t)4 * HD * KD);
    float* chS = chP + (size_t)NCHUNK * NB * HD;
    float* hin = chS + (size_t)NCHUNK * NB * HD;

    cast_x<<<MTOT * KD / 1024, 256, 0, stream>>>(x, x16);
    cast_w<<<dim3(HD * KD / 1024, 4), 256, 0, stream>>>(Bw, Dw, Wg, Cw, w16);

    in_gemm_mfma<<<dim3(MTOT / 128, HD / 64), 256, 0, stream>>>(
        (const short*)x16, (const short*)w16, Avec, bias_h, a_buf, b_buf, y);

    const int scan_threads = NB * HD * NCHUNK;
    scan_pass1<<<scan_threads / 256, 256, 0, stream>>>(a_buf, b_buf, chP, chS);
    scan_pass2<<<(NB * HD) / 256, 256, 0, stream>>>(chP, chS, hin);
    scan_pass3<<<scan_threads / 256, 256, 0, stream>>>(a_buf, b_buf, hin, x16);

    out_gemm_mfma<<<dim3(MTOT / 128, HD / 128), 256, 0, stream>>>(
        (const short*)x16, (const short*)(w16 + (size_t)3 * HD * KD), bias_y, y);
}

// Round 3
// 272.607 us; speedup vs baseline: 3.6223x; 1.0653x over previous
//
#include <hip/hip_runtime.h>
#include <math.h>

#define MTOT 32768   // BATCH * SEQ_LEN
#define KD 512       // INPUT_DIM
#define HD 512       // HIDDEN_DIM
#define NB 8         // BATCH
#define TS 4096      // SEQ_LEN
#define NCHUNK 64
#define TCHUNK 64

typedef __attribute__((ext_vector_type(8))) short bf16x8;
typedef __attribute__((ext_vector_type(4))) float f32x4;
typedef __attribute__((ext_vector_type(4))) unsigned short us4;

// async 16B global->LDS copy: lane l writes lds_base + l*16
#define GLD16(gsrc, ldst) __builtin_amdgcn_global_load_lds( \
    (const __attribute__((address_space(1))) void*)(gsrc),   \
    (__attribute__((address_space(3))) void*)(ldst), 16, 0, 0)

__device__ __forceinline__ unsigned short f2bf(float f) {
    unsigned u = __float_as_uint(f);
    return (unsigned short)((u + 0x7FFFu + ((u >> 16) & 1u)) >> 16);
}
__device__ __forceinline__ float bf2f(unsigned short u) {
    return __uint_as_float(((unsigned)u) << 16);
}

// ---------------- casts ----------------
__global__ __launch_bounds__(256) void cast_x(const float* __restrict__ src,
                                              unsigned short* __restrict__ dst) {
    const int i = (blockIdx.x * 256 + threadIdx.x) * 4;
    float4 v = *(const float4*)(src + i);
    us4 o; o.x = f2bf(v.x); o.y = f2bf(v.y); o.z = f2bf(v.z); o.w = f2bf(v.w);
    *(us4*)(dst + i) = o;
}

__global__ __launch_bounds__(256) void cast_w(const float* __restrict__ B,
                                              const float* __restrict__ D,
                                              const float* __restrict__ G,
                                              const float* __restrict__ C,
                                              unsigned short* __restrict__ dst) {
    const float* srcs[4] = {B, D, G, C};
    const float* s = srcs[blockIdx.y];
    unsigned short* d = dst + (size_t)blockIdx.y * (HD * KD);
    const int i = (blockIdx.x * 256 + threadIdx.x) * 4;
    float4 v = *(const float4*)(s + i);
    us4 o; o.x = f2bf(v.x); o.y = f2bf(v.y); o.z = f2bf(v.z); o.w = f2bf(v.w);
    *(us4*)(d + i) = o;
}

// ---------------- fused input GEMMs (bf16 MFMA) + chunk-local scan ----------------
// Per (m,h): s = g*(1-A), b = g*(xB+bias_h)  -> packed bf16 pair in ab16
//            xd = x@D^T (bf16)               -> xd16
// Per (chunk,h): (P,S) = prod/scan of (a=1-s, b) over the 64-step chunk -> chPS[bh][c]
// block tile: 128(M) x 64(N), BK=64; wave tile 64x32; block holds exactly 2 chunks.
__global__ __launch_bounds__(256, 2) void in_gemm_mfma(
    const short* __restrict__ xb, const short* __restrict__ wmat,  // wmat: B,D,G packed
    const float* __restrict__ Avec, const float* __restrict__ bias_h,
    unsigned* __restrict__ ab16, unsigned short* __restrict__ xd16,
    float2* __restrict__ chPS)
{
    __shared__ __align__(16) short Xs[128 * 64];
    __shared__ __align__(16) short Ws[3][64 * 64];
    const int tid = threadIdx.x;
    const int w = tid >> 6, l = tid & 63;
    const int m0 = blockIdx.x * 128;
    const int n0 = blockIdx.y * 64;
    const int wm = (w & 1) * 64;
    const int wn = (w >> 1) * 32;

    int xsrc[4], xdst[4];
    #pragma unroll
    for (int j = 0; j < 4; ++j) {
        const int s = (w * 4 + j) * 64 + l;
        const int r = s >> 3, g = (s & 7) ^ (r & 7);
        xsrc[j] = (m0 + r) * KD + g * 8;
        xdst[j] = (w * 4 + j) * 64 * 8;
    }
    int wsrc[2], wdst[2];
    #pragma unroll
    for (int j = 0; j < 2; ++j) {
        const int s = (w * 2 + j) * 64 + l;
        const int r = s >> 3, g = (s & 7) ^ (r & 7);
        wsrc[j] = (n0 + r) * KD + g * 8;
        wdst[j] = (w * 2 + j) * 64 * 8;
    }

    f32x4 acc[3][4][2];
    #pragma unroll
    for (int a = 0; a < 3; ++a)
        #pragma unroll
        for (int i = 0; i < 4; ++i)
            #pragma unroll
            for (int j = 0; j < 2; ++j) acc[a][i][j] = (f32x4)0.0f;

    for (int kk = 0; kk < KD; kk += 64) {
        __syncthreads();
        #pragma unroll
        for (int j = 0; j < 4; ++j) GLD16(xb + xsrc[j] + kk, Xs + xdst[j]);
        #pragma unroll
        for (int mat = 0; mat < 3; ++mat)
            #pragma unroll
            for (int j = 0; j < 2; ++j)
                GLD16(wmat + (size_t)mat * (HD * KD) + wsrc[j] + kk, &Ws[mat][wdst[j]]);
        __syncthreads();
        #pragma unroll
        for (int kc = 0; kc < 2; ++kc) {
            const int g = kc * 4 + (l >> 4);
            bf16x8 af[4];
            #pragma unroll
            for (int mt = 0; mt < 4; ++mt) {
                const int r = wm + mt * 16 + (l & 15);
                af[mt] = *(const bf16x8*)(Xs + r * 64 + ((g ^ (r & 7)) * 8));
            }
            #pragma unroll
            for (int mat = 0; mat < 3; ++mat) {
                #pragma unroll
                for (int nt = 0; nt < 2; ++nt) {
                    const int r = wn + nt * 16 + (l & 15);
                    bf16x8 bfv = *(const bf16x8*)(&Ws[mat][r * 64 + ((g ^ (r & 7)) * 8)]);
                    #pragma unroll
                    for (int mt = 0; mt < 4; ++mt)
                        acc[mat][mt][nt] = __builtin_amdgcn_mfma_f32_16x16x32_bf16(
                            af[mt], bfv, acc[mat][mt][nt], 0, 0, 0);
                }
            }
        }
    }

    // epilogue: C/D layout col = l&15, row = (l>>4)*4 + reg
    const int q  = l >> 4;
    const int cl = l & 15;
    const int bidx   = m0 >> 12;                       // m0 / TS
    const int c_in_b = ((m0 & (TS - 1)) >> 6) + (w & 1);
    #pragma unroll
    for (int nt = 0; nt < 2; ++nt) {
        const int n = n0 + wn + nt * 16 + cl;
        const float An1 = 1.0f - Avec[n];
        const float bh  = bias_h[n];
        float Pc = 1.0f, Sc = 0.0f;    // chunk-running aggregate
        #pragma unroll
        for (int mt = 0; mt < 4; ++mt) {
            float Pl = 1.0f, Sl = 0.0f;  // this lane's 4 consecutive t
            #pragma unroll
            for (int r = 0; r < 4; ++r) {
                const float vB = acc[0][mt][nt][r];
                const float vG = acc[2][mt][nt][r];
                float g = 1.0f / (1.0f + expf(-vG));
                g = fminf(fmaxf(g, 0.05f), 0.95f);
                const unsigned short su = f2bf(g * An1);
                const unsigned short bu = f2bf(g * (vB + bh));
                const float a  = 1.0f - bf2f(su);
                const float bb = bf2f(bu);
                const int m = m0 + wm + mt * 16 + q * 4 + r;
                const size_t off = (size_t)m * HD + n;
                ab16[off] = (unsigned)su | ((unsigned)bu << 16);
                xd16[off] = f2bf(acc[1][mt][nt][r]);
                Sl = fmaf(a, Sl, bb);
                Pl *= a;
            }
            // combine across the 4 quad-lanes (t order = q order)
            float Pm = 1.0f, Sm = 0.0f;
            #pragma unroll
            for (int k = 0; k < 4; ++k) {
                const float Pk = __shfl(Pl, cl + 16 * k, 64);
                const float Sk = __shfl(Sl, cl + 16 * k, 64);
                Sm = fmaf(Pk, Sm, Sk);
                Pm *= Pk;
            }
            Sc = fmaf(Pm, Sc, Sm);
            Pc *= Pm;
        }
        if (q == 0) {
            const size_t bh_i = (size_t)bidx * HD + n;
            chPS[bh_i * NCHUNK + c_in_b] = make_float2(Pc, Sc);
        }
    }
}

// ---------------- chunk chain: entry state per chunk ----------------
__global__ __launch_bounds__(256) void scan_pass2(
    const float2* __restrict__ chPS, float* __restrict__ hin)
{
    const int bh = blockIdx.x * blockDim.x + threadIdx.x;
    const float2* p = chPS + (size_t)bh * NCHUNK;
    float h = 0.0f;
    #pragma unroll
    for (int c = 0; c < NCHUNK; ++c) {
        hin[(size_t)c * (NB * HD) + bh] = h;
        const float2 ps = p[c];
        h = fmaf(ps.x, h, ps.y);
    }
}

// ---------------- pass3: replay chunks, write hs (bf16) ----------------
__global__ __launch_bounds__(256) void scan_pass3(
    const unsigned* __restrict__ ab, const float* __restrict__ hin,
    unsigned short* __restrict__ hs_out)
{
    const int g = blockIdx.x * blockDim.x + threadIdx.x;
    const int h = g & (HD - 1);
    const int rest = g >> 9;
    const int b = rest & (NB - 1);
    const int c = rest >> 3;
    size_t idx = ((size_t)(b * TS + c * TCHUNK)) * HD + h;
    float hv = hin[(size_t)c * (NB * HD) + b * HD + h];
    #pragma unroll 4
    for (int t = 0; t < TCHUNK; ++t) {
        const unsigned v = ab[idx];
        const float a  = 1.0f - bf2f((unsigned short)(v & 0xFFFFu));
        const float bb = bf2f((unsigned short)(v >> 16));
        hv = fmaf(a, hv, bb);
        hs_out[idx] = f2bf(hv);
        idx += HD;
    }
}

// ---------------- output GEMM (bf16 MFMA): y = (hs@C^T + xD + bias_y)*scale ----------------
__global__ __launch_bounds__(256, 2) void out_gemm_mfma(
    const short* __restrict__ hs, const short* __restrict__ Cb,
    const unsigned short* __restrict__ xd16,
    const float* __restrict__ bias_y, float* __restrict__ y)
{
    __shared__ __align__(16) short Hs[128 * 64];
    __shared__ __align__(16) short Cs[128 * 64];
    const int tid = threadIdx.x;
    const int w = tid >> 6, l = tid & 63;
    const int m0 = blockIdx.x * 128;
    const int n0 = blockIdx.y * 128;
    const int wm = (w & 1) * 64;
    const int wn = (w >> 1) * 64;

    int src_h[4], src_c[4], dst_s[4];
    #pragma unroll
    for (int j = 0; j < 4; ++j) {
        const int s = (w * 4 + j) * 64 + l;
        const int r = s >> 3, g = (s & 7) ^ (r & 7);
        src_h[j] = (m0 + r) * HD + g * 8;
        src_c[j] = (n0 + r) * HD + g * 8;
        dst_s[j] = (w * 4 + j) * 64 * 8;
    }

    f32x4 acc[4][4];
    #pragma unroll
    for (int i = 0; i < 4; ++i)
        #pragma unroll
        for (int j = 0; j < 4; ++j) acc[i][j] = (f32x4)0.0f;

    for (int kk = 0; kk < HD; kk += 64) {
        __syncthreads();
        #pragma unroll
        for (int j = 0; j < 4; ++j) {
            GLD16(hs + src_h[j] + kk, Hs + dst_s[j]);
            GLD16(Cb + src_c[j] + kk, Cs + dst_s[j]);
        }
        __syncthreads();
        #pragma unroll
        for (int kc = 0; kc < 2; ++kc) {
            const int g = kc * 4 + (l >> 4);
            bf16x8 af[4], bfv[4];
            #pragma unroll
            for (int t = 0; t < 4; ++t) {
                const int ra = wm + t * 16 + (l & 15);
                af[t] = *(const bf16x8*)(Hs + ra * 64 + ((g ^ (ra & 7)) * 8));
                const int rb = wn + t * 16 + (l & 15);
                bfv[t] = *(const bf16x8*)(Cs + rb * 64 + ((g ^ (rb & 7)) * 8));
            }
            #pragma unroll
            for (int mt = 0; mt < 4; ++mt)
                #pragma unroll
                for (int nt = 0; nt < 4; ++nt)
                    acc[mt][nt] = __builtin_amdgcn_mfma_f32_16x16x32_bf16(
                        af[mt], bfv[nt], acc[mt][nt], 0, 0, 0);
        }
    }

    const float scale = 0.04419417382415922f;  // 1/sqrt(512)
    #pragma unroll
    for (int nt = 0; nt < 4; ++nt) {
        const int n = n0 + wn + nt * 16 + (l & 15);
        const float by = bias_y[n];
        #pragma unroll
        for (int mt = 0; mt < 4; ++mt) {
            #pragma unroll
            for (int r = 0; r < 4; ++r) {
                const int m = m0 + wm + mt * 16 + (l >> 4) * 4 + r;
                const size_t off = (size_t)m * HD + n;
                y[off] = (acc[mt][nt][r] + bf2f(xd16[off]) + by) * scale;
            }
        }
    }
}

extern "C" void kernel_launch(void* const* d_in, const int* in_sizes, int n_in,
                              void* d_out, int out_size, void* d_ws, size_t ws_size,
                              hipStream_t stream) {
    const float* x      = (const float*)d_in[0];
    const float* Avec   = (const float*)d_in[1];
    const float* Bw     = (const float*)d_in[2];
    const float* Cw     = (const float*)d_in[3];
    const float* Dw     = (const float*)d_in[4];
    const float* Wg     = (const float*)d_in[5];
    const float* bias_h = (const float*)d_in[6];
    const float* bias_y = (const float*)d_in[7];
    float* y = (float*)d_out;

    unsigned* ab16       = (unsigned*)d_ws;                                // 64 MiB
    unsigned short* xd16 = (unsigned short*)(ab16 + (size_t)MTOT * HD);    // 32 MiB
    unsigned short* x16  = xd16 + (size_t)MTOT * HD;                       // 32 MiB, reused as hs
    unsigned short* w16  = x16 + (size_t)MTOT * HD;                        // 2 MiB
    float2* chPS = (float2*)(w16 + (size_t)4 * HD * KD);                   // 2 MiB
    float* hin   = (float*)(chPS + (size_t)NB * HD * NCHUNK);              // 1 MiB

    cast_x<<<MTOT * KD / 1024, 256, 0, stream>>>(x, x16);
    cast_w<<<dim3(HD * KD / 1024, 4), 256, 0, stream>>>(Bw, Dw, Wg, Cw, w16);

    in_gemm_mfma<<<dim3(MTOT / 128, HD / 64), 256, 0, stream>>>(
        (const short*)x16, (const short*)w16, Avec, bias_h, ab16, xd16, chPS);

    scan_pass2<<<(NB * HD) / 256, 256, 0, stream>>>(chPS, hin);
    scan_pass3<<<(NB * HD * NCHUNK) / 256, 256, 0, stream>>>(ab16, hin, x16);

    out_gemm_mfma<<<dim3(MTOT / 128, HD / 128), 256, 0, stream>>>(
        (const short*)x16, (const short*)(w16 + (size_t)3 * HD * KD), xd16, bias_y, y);
}

// Round 4
// 248.949 us; speedup vs baseline: 3.9666x; 1.0950x over previous
//
#include <hip/hip_runtime.h>
#include <math.h>

#define MTOT 32768   // BATCH * SEQ_LEN
#define KD 512       // INPUT_DIM
#define HD 512       // HIDDEN_DIM
#define NB 8         // BATCH
#define TS 4096      // SEQ_LEN
#define NCHUNK 64
#define TCHUNK 64

typedef __attribute__((ext_vector_type(8))) short bf16x8;
typedef __attribute__((ext_vector_type(4))) float f32x4;
typedef __attribute__((ext_vector_type(4))) unsigned short us4;

// async 16B global->LDS copy: lane l writes lds_base + l*16
#define GLD16(gsrc, ldst) __builtin_amdgcn_global_load_lds( \
    (const __attribute__((address_space(1))) void*)(gsrc),   \
    (__attribute__((address_space(3))) void*)(ldst), 16, 0, 0)

__device__ __forceinline__ unsigned short f2bf(float f) {
    unsigned u = __float_as_uint(f);
    return (unsigned short)((u + 0x7FFFu + ((u >> 16) & 1u)) >> 16);
}
__device__ __forceinline__ float bf2f(unsigned short u) {
    return __uint_as_float(((unsigned)u) << 16);
}

// ---------------- one cast kernel: x -> x16, {B,G,C,D} -> w16 ----------------
__global__ __launch_bounds__(256) void cast_all(
    const float* __restrict__ x, const float* __restrict__ B,
    const float* __restrict__ G, const float* __restrict__ C,
    const float* __restrict__ D,
    unsigned short* __restrict__ x16, unsigned short* __restrict__ w16)
{
    const int blk = blockIdx.x;
    const float* src;
    unsigned short* dst;
    int i;
    if (blk < (MTOT * KD / 1024)) {
        src = x; dst = x16;
        i = blk * 1024 + threadIdx.x * 4;
    } else {
        const int r = blk - (MTOT * KD / 1024);
        const int mat = r >> 8;                    // 256 blocks per matrix
        src = (mat == 0) ? B : (mat == 1) ? G : (mat == 2) ? C : D;
        dst = w16 + (size_t)mat * (HD * KD);
        i = (r & 255) * 1024 + threadIdx.x * 4;
    }
    float4 v = *(const float4*)(src + i);
    us4 o; o.x = f2bf(v.x); o.y = f2bf(v.y); o.z = f2bf(v.z); o.w = f2bf(v.w);
    *(us4*)(dst + i) = o;
}

// ---------------- fused input GEMMs (B,G) + chunk-local scan ----------------
// Per (m,h): g = clip(sigmoid(x·Wg), .05, .95); s = g*(1-A); b = g*(x·B + bias_h)
//   -> ab16[m,h] = pack(su, bu)
// Per (chunk,h): (P,S) over 64 steps -> chPS[c][bh]
// block 128(M) x 64(N), BK=64; 4 waves of 64x32; block = 2 chunks exactly.
__global__ __launch_bounds__(256, 3) void in_gemm_mfma(
    const short* __restrict__ xb, const short* __restrict__ wmat,  // B, G packed
    const float* __restrict__ Avec, const float* __restrict__ bias_h,
    unsigned* __restrict__ ab16, float2* __restrict__ chPS)
{
    __shared__ __align__(16) short Xs[128 * 64];
    __shared__ __align__(16) short Ws[2][64 * 64];
    const int tid = threadIdx.x;
    const int w = tid >> 6, l = tid & 63;
    const int m0 = blockIdx.x * 128;
    const int n0 = blockIdx.y * 64;
    const int wm = (w & 1) * 64;
    const int wn = (w >> 1) * 32;

    int xsrc[4], xdst[4];
    #pragma unroll
    for (int j = 0; j < 4; ++j) {
        const int s = (w * 4 + j) * 64 + l;
        const int r = s >> 3, g = (s & 7) ^ (r & 7);
        xsrc[j] = (m0 + r) * KD + g * 8;
        xdst[j] = (w * 4 + j) * 64 * 8;
    }
    int wsrc[2], wdst[2];
    #pragma unroll
    for (int j = 0; j < 2; ++j) {
        const int s = (w * 2 + j) * 64 + l;
        const int r = s >> 3, g = (s & 7) ^ (r & 7);
        wsrc[j] = (n0 + r) * KD + g * 8;
        wdst[j] = (w * 2 + j) * 64 * 8;
    }

    f32x4 acc[2][4][2];
    #pragma unroll
    for (int a = 0; a < 2; ++a)
        #pragma unroll
        for (int i = 0; i < 4; ++i)
            #pragma unroll
            for (int j = 0; j < 2; ++j) acc[a][i][j] = (f32x4)0.0f;

    for (int kk = 0; kk < KD; kk += 64) {
        __syncthreads();
        #pragma unroll
        for (int j = 0; j < 4; ++j) GLD16(xb + xsrc[j] + kk, Xs + xdst[j]);
        #pragma unroll
        for (int mat = 0; mat < 2; ++mat)
            #pragma unroll
            for (int j = 0; j < 2; ++j)
                GLD16(wmat + (size_t)mat * (HD * KD) + wsrc[j] + kk, &Ws[mat][wdst[j]]);
        __syncthreads();
        #pragma unroll
        for (int kc = 0; kc < 2; ++kc) {
            const int g = kc * 4 + (l >> 4);
            bf16x8 af[4];
            #pragma unroll
            for (int mt = 0; mt < 4; ++mt) {
                const int r = wm + mt * 16 + (l & 15);
                af[mt] = *(const bf16x8*)(Xs + r * 64 + ((g ^ (r & 7)) * 8));
            }
            #pragma unroll
            for (int mat = 0; mat < 2; ++mat) {
                #pragma unroll
                for (int nt = 0; nt < 2; ++nt) {
                    const int r = wn + nt * 16 + (l & 15);
                    bf16x8 bfv = *(const bf16x8*)(&Ws[mat][r * 64 + ((g ^ (r & 7)) * 8)]);
                    #pragma unroll
                    for (int mt = 0; mt < 4; ++mt)
                        acc[mat][mt][nt] = __builtin_amdgcn_mfma_f32_16x16x32_bf16(
                            af[mt], bfv, acc[mat][mt][nt], 0, 0, 0);
                }
            }
        }
    }

    // epilogue: C/D layout col = l&15, row = (l>>4)*4 + reg
    const int q  = l >> 4;
    const int cl = l & 15;
    const int bidx   = m0 >> 12;
    const int c_in_b = ((m0 & (TS - 1)) >> 6) + (w & 1);
    #pragma unroll
    for (int nt = 0; nt < 2; ++nt) {
        const int n = n0 + wn + nt * 16 + cl;
        const float An1 = 1.0f - Avec[n];
        const float bh  = bias_h[n];
        float Pc = 1.0f, Sc = 0.0f;
        #pragma unroll
        for (int mt = 0; mt < 4; ++mt) {
            float Pl = 1.0f, Sl = 0.0f;
            #pragma unroll
            for (int r = 0; r < 4; ++r) {
                const float vB = acc[0][mt][nt][r];
                const float vG = acc[1][mt][nt][r];
                float g = __builtin_amdgcn_rcpf(1.0f + __expf(-vG));
                g = fminf(fmaxf(g, 0.05f), 0.95f);
                const unsigned short su = f2bf(g * An1);
                const unsigned short bu = f2bf(g * (vB + bh));
                const float a  = 1.0f - bf2f(su);
                const float bb = bf2f(bu);
                const int m = m0 + wm + mt * 16 + q * 4 + r;
                ab16[(size_t)m * HD + n] = (unsigned)su | ((unsigned)bu << 16);
                Sl = fmaf(a, Sl, bb);
                Pl *= a;
            }
            float Pm = 1.0f, Sm = 0.0f;
            #pragma unroll
            for (int k = 0; k < 4; ++k) {
                const float Pk = __shfl(Pl, cl + 16 * k, 64);
                const float Sk = __shfl(Sl, cl + 16 * k, 64);
                Sm = fmaf(Pk, Sm, Sk);
                Pm *= Pk;
            }
            Sc = fmaf(Pm, Sc, Sm);
            Pc *= Pm;
        }
        if (q == 0) {
            chPS[(size_t)c_in_b * (NB * HD) + bidx * HD + n] = make_float2(Pc, Sc);
        }
    }
}

// ---------------- pass3: chain chunk prefix, replay, write hs (bf16) --------
__global__ __launch_bounds__(256) void scan_pass3(
    const unsigned* __restrict__ ab, const float2* __restrict__ chPS,
    unsigned short* __restrict__ hs_out)
{
    const int g = blockIdx.x * blockDim.x + threadIdx.x;
    const int h = g & (HD - 1);
    const int rest = g >> 9;
    const int b = rest & (NB - 1);
    const int c = rest >> 3;          // wave-uniform within a block
    // chain chunks 0..c-1 -> entry state
    const float2* p = chPS + (size_t)b * HD + h;
    float hv = 0.0f;
    for (int j = 0; j < c; ++j) {
        const float2 ps = p[(size_t)j * (NB * HD)];
        hv = fmaf(ps.x, hv, ps.y);
    }
    size_t idx = ((size_t)(b * TS + c * TCHUNK)) * HD + h;
    #pragma unroll 4
    for (int t = 0; t < TCHUNK; ++t) {
        const unsigned v = ab[idx];
        const float a  = 1.0f - bf2f((unsigned short)(v & 0xFFFFu));
        const float bb = bf2f((unsigned short)(v >> 16));
        hv = fmaf(a, hv, bb);
        hs_out[idx] = f2bf(hv);
        idx += HD;
    }
}

// ---------------- dual-A output GEMM: y = (hs@C^T + x@D^T + bias_y)*scale ----
// block 128x128, BK=64, 4 waves of 64x64; two A/B pairs share one accumulator.
__global__ __launch_bounds__(256, 2) void out_gemm_dual(
    const short* __restrict__ hs, const short* __restrict__ xb,
    const short* __restrict__ Cb, const short* __restrict__ Db,
    const float* __restrict__ bias_y, float* __restrict__ y)
{
    __shared__ __align__(16) short Hs[128 * 64];
    __shared__ __align__(16) short Xs2[128 * 64];
    __shared__ __align__(16) short Cs[128 * 64];
    __shared__ __align__(16) short Ds[128 * 64];
    const int tid = threadIdx.x;
    const int w = tid >> 6, l = tid & 63;
    const int m0 = blockIdx.x * 128;
    const int n0 = blockIdx.y * 128;
    const int wm = (w & 1) * 64;
    const int wn = (w >> 1) * 64;

    int src_m[4], src_n[4], dst_s[4];
    #pragma unroll
    for (int j = 0; j < 4; ++j) {
        const int s = (w * 4 + j) * 64 + l;
        const int r = s >> 3, g = (s & 7) ^ (r & 7);
        src_m[j] = (m0 + r) * HD + g * 8;
        src_n[j] = (n0 + r) * HD + g * 8;
        dst_s[j] = (w * 4 + j) * 64 * 8;
    }

    f32x4 acc[4][4];
    #pragma unroll
    for (int i = 0; i < 4; ++i)
        #pragma unroll
        for (int j = 0; j < 4; ++j) acc[i][j] = (f32x4)0.0f;

    for (int kk = 0; kk < HD; kk += 64) {
        __syncthreads();
        #pragma unroll
        for (int j = 0; j < 4; ++j) {
            GLD16(hs + src_m[j] + kk, Hs  + dst_s[j]);
            GLD16(xb + src_m[j] + kk, Xs2 + dst_s[j]);
            GLD16(Cb + src_n[j] + kk, Cs  + dst_s[j]);
            GLD16(Db + src_n[j] + kk, Ds  + dst_s[j]);
        }
        __syncthreads();
        #pragma unroll
        for (int kc = 0; kc < 2; ++kc) {
            const int g = kc * 4 + (l >> 4);
            {   // hs @ C^T
                bf16x8 af[4], bfv[4];
                #pragma unroll
                for (int t = 0; t < 4; ++t) {
                    const int ra = wm + t * 16 + (l & 15);
                    af[t] = *(const bf16x8*)(Hs + ra * 64 + ((g ^ (ra & 7)) * 8));
                    const int rb = wn + t * 16 + (l & 15);
                    bfv[t] = *(const bf16x8*)(Cs + rb * 64 + ((g ^ (rb & 7)) * 8));
                }
                #pragma unroll
                for (int mt = 0; mt < 4; ++mt)
                    #pragma unroll
                    for (int nt = 0; nt < 4; ++nt)
                        acc[mt][nt] = __builtin_amdgcn_mfma_f32_16x16x32_bf16(
                            af[mt], bfv[nt], acc[mt][nt], 0, 0, 0);
            }
            {   // x @ D^T
                bf16x8 af[4], bfv[4];
                #pragma unroll
                for (int t = 0; t < 4; ++t) {
                    const int ra = wm + t * 16 + (l & 15);
                    af[t] = *(const bf16x8*)(Xs2 + ra * 64 + ((g ^ (ra & 7)) * 8));
                    const int rb = wn + t * 16 + (l & 15);
                    bfv[t] = *(const bf16x8*)(Ds + rb * 64 + ((g ^ (rb & 7)) * 8));
                }
                #pragma unroll
                for (int mt = 0; mt < 4; ++mt)
                    #pragma unroll
                    for (int nt = 0; nt < 4; ++nt)
                        acc[mt][nt] = __builtin_amdgcn_mfma_f32_16x16x32_bf16(
                            af[mt], bfv[nt], acc[mt][nt], 0, 0, 0);
            }
        }
    }

    const float scale = 0.04419417382415922f;  // 1/sqrt(512)
    #pragma unroll
    for (int nt = 0; nt < 4; ++nt) {
        const int n = n0 + wn + nt * 16 + (l & 15);
        const float by = bias_y[n];
        #pragma unroll
        for (int mt = 0; mt < 4; ++mt) {
            #pragma unroll
            for (int r = 0; r < 4; ++r) {
                const int m = m0 + wm + mt * 16 + (l >> 4) * 4 + r;
                y[(size_t)m * HD + n] = (acc[mt][nt][r] + by) * scale;
            }
        }
    }
}

extern "C" void kernel_launch(void* const* d_in, const int* in_sizes, int n_in,
                              void* d_out, int out_size, void* d_ws, size_t ws_size,
                              hipStream_t stream) {
    const float* x      = (const float*)d_in[0];
    const float* Avec   = (const float*)d_in[1];
    const float* Bw     = (const float*)d_in[2];
    const float* Cw     = (const float*)d_in[3];
    const float* Dw     = (const float*)d_in[4];
    const float* Wg     = (const float*)d_in[5];
    const float* bias_h = (const float*)d_in[6];
    const float* bias_y = (const float*)d_in[7];
    float* y = (float*)d_out;

    unsigned* ab16        = (unsigned*)d_ws;                               // 64 MiB
    unsigned short* x16   = (unsigned short*)(ab16 + (size_t)MTOT * HD);   // 32 MiB
    unsigned short* hs16  = x16 + (size_t)MTOT * HD;                       // 32 MiB
    unsigned short* w16   = hs16 + (size_t)MTOT * HD;                      // 2 MiB: B,G,C,D
    float2* chPS = (float2*)(w16 + (size_t)4 * HD * KD);                   // 2 MiB

    cast_all<<<MTOT * KD / 1024 + 4 * (HD * KD / 1024), 256, 0, stream>>>(
        x, Bw, Wg, Cw, Dw, x16, w16);

    in_gemm_mfma<<<dim3(MTOT / 128, HD / 64), 256, 0, stream>>>(
        (const short*)x16, (const short*)w16, Avec, bias_h, ab16, chPS);

    scan_pass3<<<(NB * HD * NCHUNK) / 256, 256, 0, stream>>>(ab16, chPS, hs16);

    out_gemm_dual<<<dim3(MTOT / 128, HD / 128), 256, 0, stream>>>(
        (const short*)hs16, (const short*)x16,
        (const short*)(w16 + (size_t)2 * HD * KD),
        (const short*)(w16 + (size_t)3 * HD * KD), bias_y, y);
}